// Round 7
// baseline (229.022 us; speedup 1.0000x reference)
//
#include <hip/hip_runtime.h>
#include <cmath>

#define BB 2
#define TT 2048
#define NN 16
#define DD 128
#define NROWS (BB*TT*NN)          // 65536 rows of 128
#define PLANE (TT*DD)             // elements per (b,n) plane
#define KP 132                    // qkv/out-proj LDS pitch (u16): 2-way-free b64
#define TP 129                    // V-transpose LDS pitch

typedef unsigned short u16;
typedef unsigned int   u32;
typedef __attribute__((ext_vector_type(8)))  short s8v;   // 8 bf16 = 4 VGPRs
typedef __attribute__((ext_vector_type(16))) float vf16;  // MFMA 32x32 acc

// Static device-global scratch.
__device__ u16 g_Q [(size_t)NROWS * DD];   // (b,n,t,d) bf16 (pre-scaled)
__device__ u16 g_K [(size_t)NROWS * DD];   // (b,n,t,d) bf16
__device__ u16 g_VT[(size_t)NROWS * DD];   // (b,n,d,t') bf16, t' = pi-permuted
                                           // within each 16-t group: blocks [4..7]<->[8..11]

__device__ __forceinline__ u16 f2bf(float f) {
    return (u16)((__float_as_uint(f) + 0x8000u) >> 16);
}
__device__ __forceinline__ u32 pk2(float a, float b) {
    return ((__float_as_uint(a) + 0x8000u) >> 16)
         | ((__float_as_uint(b) + 0x8000u) & 0xFFFF0000u);
}
__device__ __forceinline__ void st8(u16* p, const float4& a, const float4& b) {
    uint2 lo, hi;
    lo.x = pk2(a.x, a.y); lo.y = pk2(a.z, a.w);
    hi.x = pk2(b.x, b.y); hi.y = pk2(b.z, b.w);
    *(uint2*)p       = lo;
    *(uint2*)(p + 4) = hi;
}
__device__ __forceinline__ s8v ld8(const u16* p) {      // two aligned b64 reads
    short4 a = *(const short4*)p;
    short4 b = *(const short4*)(p + 4);
    return (s8v){a.x, a.y, a.z, a.w, b.x, b.y, b.z, b.w};
}

// Barrier waiting LDS ops only.
__device__ __forceinline__ void bar_lds()
{
    asm volatile("s_waitcnt lgkmcnt(0)" ::: "memory");
    __builtin_amdgcn_sched_barrier(0);
    __builtin_amdgcn_s_barrier();
    __builtin_amdgcn_sched_barrier(0);
}
// K-loop barrier: drains the global_load_lds DMA too (issued a full
// iteration earlier -> cheap drain).
__device__ __forceinline__ void bar_vm()
{
    asm volatile("s_waitcnt vmcnt(0) lgkmcnt(0)" ::: "memory");
    __builtin_amdgcn_sched_barrier(0);
    __builtin_amdgcn_s_barrier();
    __builtin_amdgcn_sched_barrier(0);
}
// Direct global->LDS DMA: dest = wave-uniform base + lane*16 (linear).
__device__ __forceinline__ void gl_lds(const u16* g, u16* l)
{
    __builtin_amdgcn_global_load_lds(
        (const __attribute__((address_space(1))) void*)g,
        (__attribute__((address_space(3))) void*)l, 16, 0, 0);
}

// ---------------------------------------------------------------------------
// Fused QKV projection + V transpose (pi-permuted g_VT write).
// Identical to round 6 (verified twice).
// ---------------------------------------------------------------------------
__global__ __launch_bounds__(256)
void qkv_proj_kernel(const float* __restrict__ x,
                     const float* __restrict__ Wq, const float* __restrict__ Bq,
                     const float* __restrict__ Wk, const float* __restrict__ Bk,
                     const float* __restrict__ Wv, const float* __restrict__ Bv)
{
    __shared__ u16 Xs[128*KP];      // reused (pitch TP) for V transpose
    __shared__ u16 Ws[128*KP];

    const int t    = threadIdx.x;
    const int bnp  = blockIdx.x >> 4;          // 0..31 = b*NN+n
    const int tt0  = (blockIdx.x & 15) * 128;  // t-tile origin
    const size_t xrow0 = ((size_t)((bnp >> 4)*TT + tt0)*NN + (bnp & 15)) * DD;

    #pragma unroll
    for (int it = 0; it < 8; ++it) {
        int i = t + 256*it;
        int e = i >> 4, c8 = i & 15;
        const float* xp = x + xrow0 + (size_t)e*(NN*DD) + c8*8;
        st8(&Xs[e*KP + c8*8], *(const float4*)xp, *(const float4*)(xp + 4));
    }
    #pragma unroll
    for (int it = 0; it < 8; ++it) {
        int i = t + 256*it;
        int e = i >> 4, c8 = i & 15;
        st8(&Ws[e*KP + c8*8], ((const float4*)Wq)[2*i], ((const float4*)Wq)[2*i + 1]);
    }
    __syncthreads();

    const int w   = t >> 6;
    const int l31 = t & 31;
    const int q2  = (t >> 5) & 1;

    s8v af[8];
    #pragma unroll
    for (int s = 0; s < 8; ++s)
        af[s] = ld8(&Xs[(w*32 + l31)*KP + s*16 + q2*8]);

    #pragma unroll
    for (int wsel = 0; wsel < 3; ++wsel) {
        const float* Bi = (wsel == 0) ? Bq : (wsel == 1) ? Bk : Bv;

        vf16 acc[4];
        #pragma unroll
        for (int et = 0; et < 4; ++et)
            #pragma unroll
            for (int i = 0; i < 16; ++i) acc[et][i] = 0.f;

        #pragma unroll
        for (int s = 0; s < 8; ++s) {
            #pragma unroll
            for (int et = 0; et < 4; ++et) {
                s8v bf = ld8(&Ws[(et*32 + l31)*KP + s*16 + q2*8]);
                acc[et] = __builtin_amdgcn_mfma_f32_32x32x16_bf16(af[s], bf, acc[et], 0, 0, 0);
            }
        }

        float bb[4];
        #pragma unroll
        for (int et = 0; et < 4; ++et) bb[et] = Bi[et*32 + l31];

        if (wsel < 2) {
            u16* Ot = (wsel == 0) ? g_Q : g_K;
            #pragma unroll
            for (int r = 0; r < 16; ++r) {
                int rl = (r & 3) + 8*(r >> 2) + 4*q2;
                size_t orow = (size_t)bnp*PLANE + (size_t)(tt0 + w*32 + rl)*DD;
                #pragma unroll
                for (int et = 0; et < 4; ++et) {
                    float ov = acc[et][r] + bb[et];
                    if (wsel == 0) ov *= 0.12752053685940512f;  // (1/sqrt(128))*log2(e)
                    Ot[orow + et*32 + l31] = f2bf(ov);
                }
            }
            const float* Wn = (wsel == 0) ? Wk : Wv;
            __syncthreads();
            #pragma unroll
            for (int it = 0; it < 8; ++it) {
                int i = t + 256*it;
                int e = i >> 4, c8 = i & 15;
                st8(&Ws[e*KP + c8*8], ((const float4*)Wn)[2*i], ((const float4*)Wn)[2*i + 1]);
            }
            __syncthreads();
        } else {
            // V: transpose through LDS; write g_VT pi-permuted.
            u16* Xt = (u16*)Xs;
            #pragma unroll
            for (int r = 0; r < 16; ++r) {
                int rl = (r & 3) + 8*(r >> 2) + 4*q2;
                int row = w*32 + rl;
                #pragma unroll
                for (int et = 0; et < 4; ++et)
                    Xt[row*TP + et*32 + l31] = f2bf(acc[et][r] + bb[et]);
            }
            __syncthreads();
            const size_t vbase = (size_t)bnp*PLANE + tt0;
            #pragma unroll
            for (int c = 0; c < 8; ++c) {
                int idx = t + 256*c;            // 0..2047
                int d = idx >> 4, pc = idx & 15;
                int G = pc >> 1, h = pc & 1;
                u16 e8[8];
                #pragma unroll
                for (int i = 0; i < 8; ++i)
                    e8[i] = Xt[(G*16 + h*4 + (i & 3) + 8*(i >> 2))*TP + d];
                uint4 pkv;
                pkv.x = (u32)e8[0] | ((u32)e8[1] << 16);
                pkv.y = (u32)e8[2] | ((u32)e8[3] << 16);
                pkv.z = (u32)e8[4] | ((u32)e8[5] << 16);
                pkv.w = (u32)e8[6] | ((u32)e8[7] << 16);
                *(uint4*)&g_VT[vbase + (size_t)d*TT + pc*8] = pkv;
            }
        }
    }
}

// ---------------------------------------------------------------------------
// MFMA flash attention, k-split with spill-proof register budget:
//   4 waves = 2 q-halves (64 q each) x 2 k-halves (32 k each).
//   Register trims vs round 6 (which spilled ~3 regs -> +43 MB HBM scratch):
//   (1) P packed to pf[2][2] right after softmax -> accS dies before PV;
//   (2) causal mask via 1-VGPR threshold vs compile-time CR[r];
//   (3) cross-half l-sum deferred to one shfl_xor after the K-loop (exact).
//   Staging via global_load_lds (linear dest, XOR-swizzled source+read).
//   Ring-2, one bar_vm per tile. Fixed-shift softmax (exact).
// ---------------------------------------------------------------------------
__global__ __launch_bounds__(256, 2)
void attn_kernel(const float* __restrict__ Wp, const float* __restrict__ Bp,
                 float* __restrict__ out)
{
    // flat LDS: K bufs u16[0..16383] (2 x 64 rows x 128), V bufs [16384..32767]
    // epilogue: C fp32[16384] @0, LF fp32[128] @byte 65536, Os @0, Wps @u16 16896
    __shared__ __align__(16) u16 S[33792];   // 67.6 KB -> 2 blocks/CU

    const int t   = threadIdx.x;
    const int grp = blockIdx.x >> 5;              // 0..15
    const int bn  = blockIdx.x & 31;
    const int qt  = (grp < 8) ? (15 - grp) : (grp - 8);  // uniform-sum pairs
    const int q0  = qt * 128;
    const size_t plane = (size_t)bn * PLANE;
    const u16* Kg = g_K  + plane;
    const u16* Vg = g_VT + plane;

    const int w    = t >> 6;
    const int lane = t & 63;
    const int l31  = lane & 31;
    const int q2   = lane >> 5;
    const int qb   = (w >> 1) * 64;       // wave's q-half: 0 or 64
    const int kh   = (w & 1) * 32;        // wave's k-half: 0 or 32

    // Q fragments for the wave's two 32-q blocks (resident all iterations)
    s8v qf[2][8];
    #pragma unroll
    for (int qs = 0; qs < 2; ++qs) {
        const u16* Qg = g_Q + plane + (size_t)(q0 + qb + qs*32 + l31) * DD;
        #pragma unroll
        for (int s = 0; s < 8; ++s)
            qf[qs][s] = *(const s8v*)&Qg[s*16 + q2*8];
    }

    vf16 accO[2][4];
    #pragma unroll
    for (int qs = 0; qs < 2; ++qs)
        #pragma unroll
        for (int dt = 0; dt < 4; ++dt)
            #pragma unroll
            for (int i = 0; i < 16; ++i) accO[qs][dt][i] = 0.f;

    float lrow[2] = {0.f, 0.f};
    const int nkt = 2*qt + 2;

    // stage tile kt into buf via global_load_lds; source pre-swizzled;
    // all addressing transient (recomputed, not held resident).
    auto STAGE = [&](int kt, int buf) {
        const u16* Kbase = Kg + (size_t)(kt*64)*DD;
        const u16* Vbase = Vg + kt*64;
        #pragma unroll
        for (int i = 0; i < 4; ++i) {            // K: 1024B chunk = 4 rows x 256B
            int ch = w*4 + i;
            int r  = ch*4 + (lane >> 4);
            int sl = (lane & 15) ^ (r & 15);
            gl_lds(Kbase + r*DD + sl*8, &S[buf*8192 + ch*512]);
        }
        #pragma unroll
        for (int i = 0; i < 4; ++i) {            // V: 1024B chunk = 8 rows x 128B
            int ch = w*4 + i;
            int d  = ch*8 + (lane >> 3);
            int sl = (lane & 7) ^ ((d ^ (d >> 3)) & 7);
            gl_lds(Vbase + (size_t)d*TT + sl*8, &S[16384 + buf*8192 + ch*512]);
        }
    };

    STAGE(0, 0);
    for (int kt = 0; kt < nkt; ++kt) {
        const int cb = kt & 1;
        bar_vm();                         // tile kt staged (DMA'd 1 iter ago)
        if (kt + 1 < nkt) STAGE(kt + 1, cb ^ 1);

        const int k0 = kt*64;
        if (k0 + kh <= q0 + qb + 63) {
            const u16* Kb = &S[cb*8192];
            const u16* Vb = &S[16384 + cb*8192];

            // ---- S^T = K-half x Q^T (both q-blocks share each K frag) ----
            vf16 accS[2];
            #pragma unroll
            for (int qs = 0; qs < 2; ++qs)
                #pragma unroll
                for (int i = 0; i < 16; ++i) accS[qs][i] = 0.f;
            __builtin_amdgcn_s_setprio(1);
            #pragma unroll
            for (int s = 0; s < 8; ++s) {
                int r  = kh + l31;
                int sl = (2*s + q2) ^ (r & 15);
                s8v a = *(const s8v*)&Kb[r*128 + sl*8];
                accS[0] = __builtin_amdgcn_mfma_f32_32x32x16_bf16(a, qf[0][s], accS[0], 0, 0, 0);
                accS[1] = __builtin_amdgcn_mfma_f32_32x32x16_bf16(a, qf[1][s], accS[1], 0, 0, 0);
            }
            __builtin_amdgcn_s_setprio(0);

            // ---- mask + fixed-shift softmax + immediate pack (accS dies) ----
            s8v pf[2][2];
            #pragma unroll
            for (int qs = 0; qs < 2; ++qs) {
                // mask iff CR[r] > thr, CR[r]=(r&3)+8*(r>>2) compile-time
                const int  thr  = (q0 + qb + qs*32 + l31) - k0 - kh - 4*q2;
                const bool tail = (k0 + kh + 31) > (q0 + qb + qs*32);
                float ls = 0.f;
                #pragma unroll
                for (int r = 0; r < 16; ++r) {
                    float sv = accS[qs][r];
                    if (tail && ((r & 3) + 8*(r >> 2)) > thr) sv = -INFINITY;
                    float e = __builtin_amdgcn_exp2f(sv - 16.f);
                    accS[qs][r] = e;
                    ls += e;
                }
                lrow[qs] += ls;              // cross-half combine deferred
                #pragma unroll
                for (int tau = 0; tau < 2; ++tau)
                    #pragma unroll
                    for (int j = 0; j < 8; ++j)
                        pf[qs][tau][j] = (short)(__float_as_uint(accS[qs][tau*8 + j]) >> 16);
            }

            // ---- O += P x V-half (V frags shared by both q-blocks) ----
            __builtin_amdgcn_s_setprio(1);
            #pragma unroll
            for (int tau = 0; tau < 2; ++tau) {
                #pragma unroll
                for (int dt = 0; dt < 4; ++dt) {
                    int d  = dt*32 + l31;
                    int sl = ((kh >> 3) + 2*tau + q2) ^ ((d ^ (d >> 3)) & 7);
                    s8v bv = *(const s8v*)&Vb[d*64 + sl*8];
                    accO[0][dt] = __builtin_amdgcn_mfma_f32_32x32x16_bf16(pf[0][tau], bv, accO[0][dt], 0, 0, 0);
                    accO[1][dt] = __builtin_amdgcn_mfma_f32_32x32x16_bf16(pf[1][tau], bv, accO[1][dt], 0, 0, 0);
                }
            }
            __builtin_amdgcn_s_setprio(0);
        }
    }

    // deferred cross-half l-sum (exact: summation reorder only)
    lrow[0] += __shfl_xor(lrow[0], 32);
    lrow[1] += __shfl_xor(lrow[1], 32);

    // ============ combine k-halves (exact: partials just add) ============
    bar_lds();
    float* Cf = (float*)S;                  // 16384 floats (64 KB)
    float* LF = (float*)(S + 32768);        // 128 floats
    if (kh) {
        float* dst = Cf + (qb >> 6)*8192;
        #pragma unroll
        for (int qs = 0; qs < 2; ++qs)
            #pragma unroll
            for (int dt = 0; dt < 4; ++dt) {
                float* p4 = dst + (qs*4 + dt)*1024 + lane*16;
                #pragma unroll
                for (int k = 0; k < 4; ++k)
                    *(float4*)&p4[k*4] = make_float4(accO[qs][dt][4*k],   accO[qs][dt][4*k+1],
                                                     accO[qs][dt][4*k+2], accO[qs][dt][4*k+3]);
            }
        LF[qb + l31]      = lrow[0];        // both q2 halves write same value
        LF[qb + 32 + l31] = lrow[1];
    }
    bar_lds();
    u16* OsP = S;                           // 128 x KP bf16 O tile
    if (!kh) {
        const float* src = Cf + (qb >> 6)*8192;
        #pragma unroll
        for (int qs = 0; qs < 2; ++qs)
            #pragma unroll
            for (int dt = 0; dt < 4; ++dt) {
                const float* p4 = src + (qs*4 + dt)*1024 + lane*16;
                #pragma unroll
                for (int k = 0; k < 4; ++k) {
                    float4 v = *(const float4*)&p4[k*4];
                    accO[qs][dt][4*k]   += v.x;
                    accO[qs][dt][4*k+1] += v.y;
                    accO[qs][dt][4*k+2] += v.z;
                    accO[qs][dt][4*k+3] += v.w;
                }
            }
        lrow[0] += LF[qb + l31];
        lrow[1] += LF[qb + 32 + l31];
    }
    bar_lds();
    if (!kh) {
        #pragma unroll
        for (int qs = 0; qs < 2; ++qs) {
            float iv = 1.0f / lrow[qs];
            #pragma unroll
            for (int r = 0; r < 16; ++r) {
                int rl = (r & 3) + 8*(r >> 2) + 4*q2;
                float ir = __shfl(iv, rl);
                u16* op = &OsP[(qb + qs*32 + rl)*KP];
                #pragma unroll
                for (int dt = 0; dt < 4; ++dt)
                    op[dt*32 + l31] = f2bf(accO[qs][dt][r] * ir);
            }
        }
    }
    u16* Wps = S + 16896;                   // 128 x KP bf16 Wp tile
    #pragma unroll
    for (int it = 0; it < 8; ++it) {
        int i = t + 256*it;
        int e = i >> 4, c8 = i & 15;
        st8(&Wps[e*KP + c8*8], ((const float4*)Wp)[2*i], ((const float4*)Wp)[2*i + 1]);
    }
    bar_lds();

    // ================ fused output projection (round-5) ================
    {
        s8v af[8];
        #pragma unroll
        for (int s = 0; s < 8; ++s)
            af[s] = ld8(&OsP[(w*32 + l31)*KP + s*16 + q2*8]);

        vf16 acc[4];
        #pragma unroll
        for (int et = 0; et < 4; ++et)
            #pragma unroll
            for (int i = 0; i < 16; ++i) acc[et][i] = 0.f;

        #pragma unroll
        for (int s = 0; s < 8; ++s) {
            #pragma unroll
            for (int et = 0; et < 4; ++et) {
                s8v bf = ld8(&Wps[(et*32 + l31)*KP + s*16 + q2*8]);
                acc[et] = __builtin_amdgcn_mfma_f32_32x32x16_bf16(af[s], bf, acc[et], 0, 0, 0);
            }
        }

        float bb[4];
        #pragma unroll
        for (int et = 0; et < 4; ++et) bb[et] = Bp[et*32 + l31];

        const int b = bn >> 4, n = bn & 15;
        #pragma unroll
        for (int r = 0; r < 16; ++r) {
            int rl = (r & 3) + 8*(r >> 2) + 4*q2;
            int qg = q0 + w*32 + rl;
            size_t orow = ((size_t)(b*TT + qg)*NN + n) * DD;
            #pragma unroll
            for (int et = 0; et < 4; ++et)
                out[orow + et*32 + l31] = acc[et][r] + bb[et];
        }
    }
}

extern "C" void kernel_launch(void* const* d_in, const int* in_sizes, int n_in,
                              void* d_out, int out_size, void* d_ws, size_t ws_size,
                              hipStream_t stream)
{
    const float* x  = (const float*)d_in[0];
    const float* wq = (const float*)d_in[1];
    const float* bq = (const float*)d_in[2];
    const float* wk = (const float*)d_in[3];
    const float* bk = (const float*)d_in[4];
    const float* wv = (const float*)d_in[5];
    const float* bv = (const float*)d_in[6];
    const float* wp = (const float*)d_in[7];
    const float* bp = (const float*)d_in[8];
    float* out = (float*)d_out;
    (void)d_ws; (void)ws_size;

    qkv_proj_kernel<<<dim3(NROWS/128), dim3(256), 0, stream>>>(
        x, wq, bq, wk, bk, wv, bv);
    attn_kernel<<<dim3(BB*NN*(TT/128)), dim3(256), 0, stream>>>(wp, bp, out);
}

// Round 8
// 223.095 us; speedup vs baseline: 1.0266x; 1.0266x over previous
//
#include <hip/hip_runtime.h>
#include <cmath>

#define BB 2
#define TT 2048
#define NN 16
#define DD 128
#define NROWS (BB*TT*NN)          // 65536 rows of 128
#define PLANE (TT*DD)             // elements per (b,n) plane
#define KP 132                    // qkv/out-proj LDS pitch (u16): 2-way-free b64
#define TP 129                    // V-transpose LDS pitch

typedef unsigned short u16;
typedef unsigned int   u32;
typedef __attribute__((ext_vector_type(8)))  short s8v;   // 8 bf16 = 4 VGPRs
typedef __attribute__((ext_vector_type(16))) float vf16;  // MFMA 32x32 acc

// Static device-global scratch.
__device__ u16 g_Q [(size_t)NROWS * DD];   // (b,n,t,d) bf16 (pre-scaled)
__device__ u16 g_K [(size_t)NROWS * DD];   // (b,n,t,d) bf16
__device__ u16 g_VT[(size_t)NROWS * DD];   // (b,n,d,t') bf16, t' = pi-permuted
                                           // within each 16-t group: blocks [4..7]<->[8..11]

__device__ __forceinline__ u16 f2bf(float f) {
    return (u16)((__float_as_uint(f) + 0x8000u) >> 16);
}
__device__ __forceinline__ u32 pk2(float a, float b) {
    return ((__float_as_uint(a) + 0x8000u) >> 16)
         | ((__float_as_uint(b) + 0x8000u) & 0xFFFF0000u);
}
__device__ __forceinline__ void st8(u16* p, const float4& a, const float4& b) {
    uint2 lo, hi;
    lo.x = pk2(a.x, a.y); lo.y = pk2(a.z, a.w);
    hi.x = pk2(b.x, b.y); hi.y = pk2(b.z, b.w);
    *(uint2*)p       = lo;
    *(uint2*)(p + 4) = hi;
}
__device__ __forceinline__ s8v ld8(const u16* p) {      // two aligned b64 reads
    short4 a = *(const short4*)p;
    short4 b = *(const short4*)(p + 4);
    return (s8v){a.x, a.y, a.z, a.w, b.x, b.y, b.z, b.w};
}

// Barrier waiting LDS ops only (counted-vmcnt discipline: global prefetch
// loads stay in flight across the barrier; compiler inserts counted vmcnt
// at the STORET consume point). Round-4 win.
__device__ __forceinline__ void bar_lds()
{
    asm volatile("s_waitcnt lgkmcnt(0)" ::: "memory");
    __builtin_amdgcn_sched_barrier(0);
    __builtin_amdgcn_s_barrier();
    __builtin_amdgcn_sched_barrier(0);
}

// ---------------------------------------------------------------------------
// Fused QKV projection + V transpose (pi-permuted g_VT write).
// Byte-identical to rounds 6/7 (verified twice).
// ---------------------------------------------------------------------------
__global__ __launch_bounds__(256)
void qkv_proj_kernel(const float* __restrict__ x,
                     const float* __restrict__ Wq, const float* __restrict__ Bq,
                     const float* __restrict__ Wk, const float* __restrict__ Bk,
                     const float* __restrict__ Wv, const float* __restrict__ Bv)
{
    __shared__ u16 Xs[128*KP];      // reused (pitch TP) for V transpose
    __shared__ u16 Ws[128*KP];

    const int t    = threadIdx.x;
    const int bnp  = blockIdx.x >> 4;          // 0..31 = b*NN+n
    const int tt0  = (blockIdx.x & 15) * 128;  // t-tile origin
    const size_t xrow0 = ((size_t)((bnp >> 4)*TT + tt0)*NN + (bnp & 15)) * DD;

    #pragma unroll
    for (int it = 0; it < 8; ++it) {
        int i = t + 256*it;
        int e = i >> 4, c8 = i & 15;
        const float* xp = x + xrow0 + (size_t)e*(NN*DD) + c8*8;
        st8(&Xs[e*KP + c8*8], *(const float4*)xp, *(const float4*)(xp + 4));
    }
    #pragma unroll
    for (int it = 0; it < 8; ++it) {
        int i = t + 256*it;
        int e = i >> 4, c8 = i & 15;
        st8(&Ws[e*KP + c8*8], ((const float4*)Wq)[2*i], ((const float4*)Wq)[2*i + 1]);
    }
    __syncthreads();

    const int w   = t >> 6;
    const int l31 = t & 31;
    const int q2  = (t >> 5) & 1;

    s8v af[8];
    #pragma unroll
    for (int s = 0; s < 8; ++s)
        af[s] = ld8(&Xs[(w*32 + l31)*KP + s*16 + q2*8]);

    #pragma unroll
    for (int wsel = 0; wsel < 3; ++wsel) {
        const float* Bi = (wsel == 0) ? Bq : (wsel == 1) ? Bk : Bv;

        vf16 acc[4];
        #pragma unroll
        for (int et = 0; et < 4; ++et)
            #pragma unroll
            for (int i = 0; i < 16; ++i) acc[et][i] = 0.f;

        #pragma unroll
        for (int s = 0; s < 8; ++s) {
            #pragma unroll
            for (int et = 0; et < 4; ++et) {
                s8v bf = ld8(&Ws[(et*32 + l31)*KP + s*16 + q2*8]);
                acc[et] = __builtin_amdgcn_mfma_f32_32x32x16_bf16(af[s], bf, acc[et], 0, 0, 0);
            }
        }

        float bb[4];
        #pragma unroll
        for (int et = 0; et < 4; ++et) bb[et] = Bi[et*32 + l31];

        if (wsel < 2) {
            u16* Ot = (wsel == 0) ? g_Q : g_K;
            #pragma unroll
            for (int r = 0; r < 16; ++r) {
                int rl = (r & 3) + 8*(r >> 2) + 4*q2;
                size_t orow = (size_t)bnp*PLANE + (size_t)(tt0 + w*32 + rl)*DD;
                #pragma unroll
                for (int et = 0; et < 4; ++et) {
                    float ov = acc[et][r] + bb[et];
                    if (wsel == 0) ov *= 0.12752053685940512f;  // (1/sqrt(128))*log2(e)
                    Ot[orow + et*32 + l31] = f2bf(ov);
                }
            }
            const float* Wn = (wsel == 0) ? Wk : Wv;
            __syncthreads();
            #pragma unroll
            for (int it = 0; it < 8; ++it) {
                int i = t + 256*it;
                int e = i >> 4, c8 = i & 15;
                st8(&Ws[e*KP + c8*8], ((const float4*)Wn)[2*i], ((const float4*)Wn)[2*i + 1]);
            }
            __syncthreads();
        } else {
            // V: transpose through LDS; write g_VT pi-permuted.
            u16* Xt = (u16*)Xs;
            #pragma unroll
            for (int r = 0; r < 16; ++r) {
                int rl = (r & 3) + 8*(r >> 2) + 4*q2;
                int row = w*32 + rl;
                #pragma unroll
                for (int et = 0; et < 4; ++et)
                    Xt[row*TP + et*32 + l31] = f2bf(acc[et][r] + bb[et]);
            }
            __syncthreads();
            const size_t vbase = (size_t)bnp*PLANE + tt0;
            #pragma unroll
            for (int c = 0; c < 8; ++c) {
                int idx = t + 256*c;            // 0..2047
                int d = idx >> 4, pc = idx & 15;
                int G = pc >> 1, h = pc & 1;
                u16 e8[8];
                #pragma unroll
                for (int i = 0; i < 8; ++i)
                    e8[i] = Xt[(G*16 + h*4 + (i & 3) + 8*(i >> 2))*TP + d];
                uint4 pkv;
                pkv.x = (u32)e8[0] | ((u32)e8[1] << 16);
                pkv.y = (u32)e8[2] | ((u32)e8[3] << 16);
                pkv.z = (u32)e8[4] | ((u32)e8[5] << 16);
                pkv.w = (u32)e8[6] | ((u32)e8[7] << 16);
                *(uint4*)&g_VT[vbase + (size_t)d*TT + pc*8] = pkv;
            }
        }
    }
}

// ---------------------------------------------------------------------------
// MFMA flash attention — round-5 structure (register-safe, 112 VGPR) with
// b128-swizzled LDS tiles:
//   K buf: linear [64][128] u16, 16B chunk kc stored at slot kc^(row&15);
//   V buf: linear [128][64] u16, chunk vc stored at slot vc^((d^(d>>3))&7).
//   Every fragment read and staging store = ONE aligned b128, conflict-free.
//   Pi-permuted g_VT makes each PV B-fragment contiguous (one b128).
//   Ring-2, reg staging, counted-wait barrier, fixed-shift softmax (exact),
//   fused output projection epilogue. Grid: bn=blockIdx&31 -> plane's 16
//   blocks share one XCD (blockIdx%8 == bn%8) -> K/V L2-resident.
// ---------------------------------------------------------------------------
__global__ __launch_bounds__(256, 2)
void attn_kernel(const float* __restrict__ Wp, const float* __restrict__ Bp,
                 float* __restrict__ out)
{
    // K bufs: S[0..16383] (2 x 64 x 128), V bufs: S[16384..32767] (2 x 128 x 64)
    // epilogue: Os (128 x KP) @0, Wps (128 x KP) @16896
    __shared__ __align__(16) u16 S[33792];   // 67.6 KB -> 2 blocks/CU

    const int t   = threadIdx.x;
    const int grp = blockIdx.x >> 5;              // 0..15
    const int bn  = blockIdx.x & 31;
    const int qt  = (grp < 8) ? (15 - grp) : (grp - 8);  // uniform-sum pairs
    const int q0  = qt * 128;
    const size_t plane = (size_t)bn * PLANE;
    const u16* Kg = g_K  + plane;
    const u16* Vg = g_VT + plane;

    const int w      = t >> 6;
    const int lane   = t & 63;
    const int l31    = lane & 31;
    const int q2     = lane >> 5;
    const int qband  = q0 + 32*w;
    const int qrow   = qband + l31;

    s8v qf[8];
    {
        const u16* Qg = g_Q + plane + (size_t)qrow * DD;
        #pragma unroll
        for (int s = 0; s < 8; ++s)
            qf[s] = *(const s8v*)&Qg[s*16 + q2*8];
    }

    vf16 accO[4];
    #pragma unroll
    for (int dt = 0; dt < 4; ++dt)
        #pragma unroll
        for (int i = 0; i < 16; ++i) accO[dt][i] = 0.f;

    float lrow = 0.f;
    const int nkt = 2*qt + 2;

    uint4 pk[4], pv[4];

    auto LOADT = [&](int kt) {
        const u16* K2 = Kg + (size_t)(kt*64)*DD;
        const u16* V2 = Vg + kt*64;
        #pragma unroll
        for (int c = 0; c < 4; ++c) {
            int j = t + 256*c;                  // 0..1023
            int kr = j >> 4, kc = j & 15;
            pk[c] = *(const uint4*)&K2[kr*DD + kc*8];
            int vr = j >> 3, vc = j & 7;
            pv[c] = *(const uint4*)&V2[(size_t)vr*TT + vc*8];
        }
    };
    auto STORET = [&](int buf) {
        #pragma unroll
        for (int c = 0; c < 4; ++c) {
            int j = t + 256*c;
            int kr = j >> 4, kc = j & 15;
            int slk = kc ^ (kr & 15);
            *(uint4*)&S[buf*8192 + kr*128 + slk*8] = pk[c];
            int vr = j >> 3, vc = j & 7;
            int slv = vc ^ ((vr ^ (vr >> 3)) & 7);
            *(uint4*)&S[16384 + buf*8192 + vr*64 + slv*8] = pv[c];
        }
    };

    // prologue: tile 0 -> buf0; tile 1 loads in flight
    LOADT(0);
    STORET(0);
    LOADT(1);                                 // nkt >= 2 always

    for (int kt = 0; kt < nkt; ++kt) {
        const int k0 = kt*64;
        const int cb = kt & 1;
        bar_lds();                            // buf[cb] staged for all waves

        // stage tile kt+1 (loads issued one full tile ago -> counted vmcnt),
        // then issue loads for kt+2 (in flight across the next barrier).
        if (kt + 1 < nkt) {
            STORET(cb ^ 1);
            if (kt + 2 < nkt) LOADT(kt + 2);
        }

        if (k0 <= qband + 31) {
            const u16* Kb = &S[cb*8192];
            const u16* Vb = &S[16384 + cb*8192];

            // ---- S^T = K x Q^T (Q pre-scaled: already exp2 domain) ----
            vf16 accS[2];
            #pragma unroll
            for (int kk = 0; kk < 2; ++kk)
                #pragma unroll
                for (int i = 0; i < 16; ++i) accS[kk][i] = 0.f;
            __builtin_amdgcn_s_setprio(1);
            #pragma unroll
            for (int s = 0; s < 8; ++s) {
                #pragma unroll
                for (int kk = 0; kk < 2; ++kk) {
                    int r  = kk*32 + l31;
                    int sl = (2*s + q2) ^ (r & 15);
                    s8v a = *(const s8v*)&Kb[r*128 + sl*8];
                    accS[kk] = __builtin_amdgcn_mfma_f32_32x32x16_bf16(a, qf[s], accS[kk], 0, 0, 0);
                }
            }
            __builtin_amdgcn_s_setprio(0);

            // ---- causal mask (tail tiles only) ----
            float p[2][16];
            const bool tail = (k0 + 63 > qband);
            #pragma unroll
            for (int kk = 0; kk < 2; ++kk)
                #pragma unroll
                for (int r = 0; r < 16; ++r) {
                    float sv = accS[kk][r];
                    if (tail) {
                        int keyg = k0 + kk*32 + (r & 3) + 8*(r >> 2) + 4*q2;
                        if (keyg > qrow) sv = -INFINITY;
                    }
                    p[kk][r] = sv;
                }

            // ---- fixed-shift softmax: P = exp2(s - 16), exact ----
            float ls0 = 0.f, ls1 = 0.f;
            #pragma unroll
            for (int r = 0; r < 16; ++r) {
                float e0 = __builtin_amdgcn_exp2f(p[0][r] - 16.f);
                float e1 = __builtin_amdgcn_exp2f(p[1][r] - 16.f);
                p[0][r] = e0; p[1][r] = e1;
                ls0 += e0; ls1 += e1;
            }
            float ls = ls0 + ls1;
            ls += __shfl_xor(ls, 32);
            lrow += ls;

            // ---- pack P (bf16 trunc) as PV A-fragments ----
            s8v pf[4];
            #pragma unroll
            for (int tau = 0; tau < 4; ++tau) {
                int kk = tau >> 1, rb = (tau & 1)*8;
                s8v v;
                #pragma unroll
                for (int j = 0; j < 8; ++j)
                    v[j] = (short)(__float_as_uint(p[kk][rb + j]) >> 16);
                pf[tau] = v;
            }

            // ---- O += P x V (pi-permuted V: one b128 per fragment) ----
            __builtin_amdgcn_s_setprio(1);
            #pragma unroll
            for (int dt = 0; dt < 4; ++dt) {
                int d = dt*32 + l31;
                int fd = (d ^ (d >> 3)) & 7;
                #pragma unroll
                for (int tau = 0; tau < 4; ++tau) {
                    int c  = 4*(tau >> 1) + 2*(tau & 1) + q2;
                    int sl = c ^ fd;
                    s8v bv = *(const s8v*)&Vb[d*64 + sl*8];
                    accO[dt] = __builtin_amdgcn_mfma_f32_32x32x16_bf16(pf[tau], bv, accO[dt], 0, 0, 0);
                }
            }
            __builtin_amdgcn_s_setprio(0);
        }
    }

    // =================== fused output projection epilogue ===================
    bar_lds();                       // all waves done reading K/V LDS regions
    u16* Os  = &S[0];                // 128 x KP bf16 O tile
    u16* Wps = &S[16896];            // 128 x KP bf16 Wp tile

    // normalized O -> LDS (each wave writes its own 32-row band)
    {
        float inv = 1.0f / lrow;
        #pragma unroll
        for (int r = 0; r < 16; ++r) {
            int rl = (r & 3) + 8*(r >> 2) + 4*q2;
            float ir = __shfl(inv, rl);
            u16* op = &Os[(32*w + rl)*KP];
            #pragma unroll
            for (int dt = 0; dt < 4; ++dt)
                op[dt*32 + l31] = f2bf(accO[dt][r] * ir);
        }
    }
    // stage Wp (fp32 -> bf16)
    #pragma unroll
    for (int it = 0; it < 8; ++it) {
        int i = t + 256*it;
        int e = i >> 4, c8 = i & 15;
        st8(&Wps[e*KP + c8*8], ((const float4*)Wp)[2*i], ((const float4*)Wp)[2*i + 1]);
    }
    bar_lds();

    // out = O x Wp^T + bp
    {
        s8v af[8];
        #pragma unroll
        for (int s = 0; s < 8; ++s)
            af[s] = ld8(&Os[(w*32 + l31)*KP + s*16 + q2*8]);

        vf16 acc[4];
        #pragma unroll
        for (int et = 0; et < 4; ++et)
            #pragma unroll
            for (int i = 0; i < 16; ++i) acc[et][i] = 0.f;

        #pragma unroll
        for (int s = 0; s < 8; ++s) {
            #pragma unroll
            for (int et = 0; et < 4; ++et) {
                s8v bf = ld8(&Wps[(et*32 + l31)*KP + s*16 + q2*8]);
                acc[et] = __builtin_amdgcn_mfma_f32_32x32x16_bf16(af[s], bf, acc[et], 0, 0, 0);
            }
        }

        float bb[4];
        #pragma unroll
        for (int et = 0; et < 4; ++et) bb[et] = Bp[et*32 + l31];

        const int b = bn >> 4, n = bn & 15;
        #pragma unroll
        for (int r = 0; r < 16; ++r) {
            int rl = (r & 3) + 8*(r >> 2) + 4*q2;
            int qg = q0 + w*32 + rl;
            size_t orow = ((size_t)(b*TT + qg)*NN + n) * DD;
            #pragma unroll
            for (int et = 0; et < 4; ++et)
                out[orow + et*32 + l31] = acc[et][r] + bb[et];
        }
    }
}

extern "C" void kernel_launch(void* const* d_in, const int* in_sizes, int n_in,
                              void* d_out, int out_size, void* d_ws, size_t ws_size,
                              hipStream_t stream)
{
    const float* x  = (const float*)d_in[0];
    const float* wq = (const float*)d_in[1];
    const float* bq = (const float*)d_in[2];
    const float* wk = (const float*)d_in[3];
    const float* bk = (const float*)d_in[4];
    const float* wv = (const float*)d_in[5];
    const float* bv = (const float*)d_in[6];
    const float* wp = (const float*)d_in[7];
    const float* bp = (const float*)d_in[8];
    float* out = (float*)d_out;
    (void)d_ws; (void)ws_size;

    qkv_proj_kernel<<<dim3(NROWS/128), dim3(256), 0, stream>>>(
        x, wq, bq, wk, bk, wv, bv);
    attn_kernel<<<dim3(BB*NN*(TT/128)), dim3(256), 0, stream>>>(wp, bp, out);
}

// Round 9
// 172.728 us; speedup vs baseline: 1.3259x; 1.2916x over previous
//
#include <hip/hip_runtime.h>
#include <cmath>

#define BB 2
#define TT 2048
#define NN 16
#define DD 128
#define NROWS (BB*TT*NN)          // 65536 rows of 128
#define PLANE (TT*DD)             // elements per (b,n) plane
#define KP 132                    // Ks/Xs/Ws pitch (u16): 66 dw == 2 mod 32
#define VP 68                     // Vt pitch (u16): 34 dw == 2 mod 32
#define TP 129                    // V-transpose LDS pitch

typedef unsigned short u16;
typedef unsigned int   u32;
typedef __attribute__((ext_vector_type(8)))  short s8v;   // 8 bf16 = 4 VGPRs
typedef __attribute__((ext_vector_type(16))) float vf16;  // MFMA 32x32 acc

// Static device-global scratch.
__device__ u16 g_Q [(size_t)NROWS * DD];   // (b,n,t,d) bf16 (pre-scaled)
__device__ u16 g_K [(size_t)NROWS * DD];   // (b,n,t,d) bf16
__device__ u16 g_VT[(size_t)NROWS * DD];   // (b,n,d,t) bf16 = V transposed

__device__ __forceinline__ u16 f2bf(float f) {
    return (u16)((__float_as_uint(f) + 0x8000u) >> 16);
}
__device__ __forceinline__ u32 pk2(float a, float b) {
    return ((__float_as_uint(a) + 0x8000u) >> 16)
         | ((__float_as_uint(b) + 0x8000u) & 0xFFFF0000u);
}
__device__ __forceinline__ void st8(u16* p, const float4& a, const float4& b) {
    uint2 lo, hi;
    lo.x = pk2(a.x, a.y); lo.y = pk2(a.z, a.w);
    hi.x = pk2(b.x, b.y); hi.y = pk2(b.z, b.w);
    *(uint2*)p       = lo;
    *(uint2*)(p + 4) = hi;
}
__device__ __forceinline__ s8v ld8(const u16* p) {      // two aligned b64 reads
    short4 a = *(const short4*)p;
    short4 b = *(const short4*)(p + 4);
    return (s8v){a.x, a.y, a.z, a.w, b.x, b.y, b.z, b.w};
}

// Barrier WITHOUT the vmcnt(0) drain __syncthreads() forces: only LDS-write
// visibility (lgkmcnt) is needed across the workgroup. Global prefetch loads
// stay in flight; the compiler inserts a COUNTED vmcnt where the staged
// registers are consumed (T4-lite). Round-4 win: −9.5% on attn.
__device__ __forceinline__ void bar_lds()
{
    asm volatile("s_waitcnt lgkmcnt(0)" ::: "memory");
    __builtin_amdgcn_sched_barrier(0);
    __builtin_amdgcn_s_barrier();
    __builtin_amdgcn_sched_barrier(0);
}

// ---------------------------------------------------------------------------
// Fused QKV projection + V transpose (round-5 verified structure) with
// W-REGISTER-PREFETCH: the next weight tile is loaded from HBM and bf16-packed
// into 32 VGPRs BEFORE the current GEMM's MFMA loop (latency hides under
// MFMA + output writes); the restage between GEMMs becomes a pure LDS write
// (sync -> ds_write -> sync) instead of an exposed HBM round-trip.
// ---------------------------------------------------------------------------
__global__ __launch_bounds__(256)
void qkv_proj_kernel(const float* __restrict__ x,
                     const float* __restrict__ Wq, const float* __restrict__ Bq,
                     const float* __restrict__ Wk, const float* __restrict__ Bk,
                     const float* __restrict__ Wv, const float* __restrict__ Bv)
{
    __shared__ u16 Xs[128*KP];      // reused (pitch TP) for V transpose
    __shared__ u16 Ws[128*KP];

    const int t    = threadIdx.x;
    const int bnp  = blockIdx.x >> 4;          // 0..31 = b*NN+n
    const int tt0  = (blockIdx.x & 15) * 128;  // t-tile origin
    const size_t xrow0 = ((size_t)((bnp >> 4)*TT + tt0)*NN + (bnp & 15)) * DD;

    // stage X tile (fp32 -> bf16); row e = local t, stride NN*DD
    #pragma unroll
    for (int it = 0; it < 8; ++it) {
        int i = t + 256*it;
        int e = i >> 4, c8 = i & 15;
        const float* xp = x + xrow0 + (size_t)e*(NN*DD) + c8*8;
        st8(&Xs[e*KP + c8*8], *(const float4*)xp, *(const float4*)(xp + 4));
    }
    // stage Wq
    #pragma unroll
    for (int it = 0; it < 8; ++it) {
        int i = t + 256*it;
        int e = i >> 4, c8 = i & 15;
        st8(&Ws[e*KP + c8*8], ((const float4*)Wq)[2*i], ((const float4*)Wq)[2*i + 1]);
    }
    __syncthreads();

    const int w   = t >> 6;
    const int l31 = t & 31;
    const int q2  = (t >> 5) & 1;

    // A-fragments: this wave's 32-row band, in registers for all 3 GEMMs
    s8v af[8];
    #pragma unroll
    for (int s = 0; s < 8; ++s)
        af[s] = ld8(&Xs[(w*32 + l31)*KP + s*16 + q2*8]);

    uint2 wl[8], wh[8];                       // prefetched next-W (bf16-packed)

    #pragma unroll
    for (int wsel = 0; wsel < 3; ++wsel) {
        const float* Bi = (wsel == 0) ? Bq : (wsel == 1) ? Bk : Bv;

        // prefetch NEXT weight tile into registers (loads overlap the MFMA
        // loop and output writes below)
        if (wsel < 2) {
            const float* Wn = (wsel == 0) ? Wk : Wv;
            #pragma unroll
            for (int it = 0; it < 8; ++it) {
                int i = t + 256*it;
                float4 a = ((const float4*)Wn)[2*i];
                float4 b = ((const float4*)Wn)[2*i + 1];
                wl[it].x = pk2(a.x, a.y); wl[it].y = pk2(a.z, a.w);
                wh[it].x = pk2(b.x, b.y); wh[it].y = pk2(b.z, b.w);
            }
        }

        vf16 acc[4];
        #pragma unroll
        for (int et = 0; et < 4; ++et)
            #pragma unroll
            for (int i = 0; i < 16; ++i) acc[et][i] = 0.f;

        #pragma unroll
        for (int s = 0; s < 8; ++s) {
            #pragma unroll
            for (int et = 0; et < 4; ++et) {
                s8v bf = ld8(&Ws[(et*32 + l31)*KP + s*16 + q2*8]);
                acc[et] = __builtin_amdgcn_mfma_f32_32x32x16_bf16(af[s], bf, acc[et], 0, 0, 0);
            }
        }

        float bb[4];
        #pragma unroll
        for (int et = 0; et < 4; ++et) bb[et] = Bi[et*32 + l31];

        if (wsel < 2) {
            u16* Ot = (wsel == 0) ? g_Q : g_K;
            #pragma unroll
            for (int r = 0; r < 16; ++r) {
                int rl = (r & 3) + 8*(r >> 2) + 4*q2;
                size_t orow = (size_t)bnp*PLANE + (size_t)(tt0 + w*32 + rl)*DD;
                #pragma unroll
                for (int et = 0; et < 4; ++et) {
                    float ov = acc[et][r] + bb[et];
                    if (wsel == 0) ov *= 0.12752053685940512f;  // (1/sqrt(128))*log2(e)
                    Ot[orow + et*32 + l31] = f2bf(ov);
                }
            }
            // restage Ws from prefetched registers (LDS-speed, no HBM wait)
            __syncthreads();             // everyone done reading Ws
            #pragma unroll
            for (int it = 0; it < 8; ++it) {
                int i = t + 256*it;
                int e = i >> 4, c8 = i & 15;
                *(uint2*)&Ws[e*KP + c8*8]     = wl[it];
                *(uint2*)&Ws[e*KP + c8*8 + 4] = wh[it];
            }
            __syncthreads();
        } else {
            // ---- V: transpose through LDS, write g_VT (b,n,d,t) directly ----
            u16* Xt = (u16*)Xs;          // reuse, pitch TP (af already in regs)
            #pragma unroll
            for (int r = 0; r < 16; ++r) {
                int rl = (r & 3) + 8*(r >> 2) + 4*q2;
                int row = w*32 + rl;
                #pragma unroll
                for (int et = 0; et < 4; ++et)
                    Xt[row*TP + et*32 + l31] = f2bf(acc[et][r] + bb[et]);
            }
            __syncthreads();
            const size_t vbase = (size_t)bnp*PLANE + tt0;
            #pragma unroll
            for (int c = 0; c < 8; ++c) {
                int idx = t + 256*c;            // 0..2047
                int d = idx >> 4, tc = idx & 15;
                u16 e8[8];
                #pragma unroll
                for (int i = 0; i < 8; ++i) e8[i] = Xt[(tc*8 + i)*TP + d];
                uint4 pkv;
                pkv.x = (u32)e8[0] | ((u32)e8[1] << 16);
                pkv.y = (u32)e8[2] | ((u32)e8[3] << 16);
                pkv.z = (u32)e8[4] | ((u32)e8[5] << 16);
                pkv.w = (u32)e8[6] | ((u32)e8[7] << 16);
                *(uint4*)&g_VT[vbase + (size_t)d*TT + tc*8] = pkv;
            }
        }
    }
}

// ---------------------------------------------------------------------------
// MFMA flash attention + fused output projection.
// Byte-exact revert to the round-5 VERIFIED kernel (76 us, 112 VGPR,
// no spills): pitched LDS (KP/VP, 2-way-free b64 fragment reads with
// immediate offsets), ring-2, reg staging, counted-wait barrier,
// fixed-shift softmax (exact), fused out-projection epilogue.
// ---------------------------------------------------------------------------
__global__ __launch_bounds__(256, 2)
void attn_kernel(const float* __restrict__ Wp, const float* __restrict__ Bp,
                 float* __restrict__ out)
{
    __shared__ u16 Ks[2][64*KP];    // K tiles; epilogue: O tile (exact fit)
    __shared__ u16 Vt[2][128*VP];   // V tiles; epilogue: Wp tile (fits)

    const int t   = threadIdx.x;
    const int grp = blockIdx.x >> 5;              // 0..15
    const int bn  = blockIdx.x & 31;
    const int qt  = (grp < 8) ? (15 - grp) : (grp - 8);  // uniform-sum pairs
    const int q0  = qt * 128;
    const size_t plane = (size_t)bn * PLANE;
    const u16* Kg = g_K  + plane;
    const u16* Vg = g_VT + plane;

    const int w      = t >> 6;
    const int lane   = t & 63;
    const int lane31 = lane & 31;
    const int q2     = lane >> 5;
    const int qband  = q0 + 32*w;
    const int qrow   = qband + lane31;

    s8v qf[8];
    {
        const u16* Qg = g_Q + plane + (size_t)qrow * DD;
        #pragma unroll
        for (int s = 0; s < 8; ++s)
            qf[s] = *(const s8v*)&Qg[s*16 + q2*8];
    }

    vf16 accO[4];
    #pragma unroll
    for (int dt = 0; dt < 4; ++dt)
        #pragma unroll
        for (int i = 0; i < 16; ++i) accO[dt][i] = 0.f;

    float lrow = 0.f;
    const int nkt = 2*qt + 2;

    uint4 pk[4], pv[4];

    auto LOADT = [&](int kt) {
        const u16* K2 = Kg + (size_t)(kt*64)*DD;
        const u16* V2 = Vg + kt*64;
        #pragma unroll
        for (int c = 0; c < 4; ++c) {
            int j = t + 256*c;                  // 0..1023
            int kr = j >> 4, kc = j & 15;
            pk[c] = *(const uint4*)&K2[kr*DD + kc*8];
            int vr = j >> 3, vc = j & 7;
            pv[c] = *(const uint4*)&V2[(size_t)vr*TT + vc*8];
        }
    };
    auto STORET = [&](int buf) {
        #pragma unroll
        for (int c = 0; c < 4; ++c) {
            int j = t + 256*c;
            int kr = j >> 4, kc = j & 15;
            uint2 a, b;
            a.x = pk[c].x; a.y = pk[c].y; b.x = pk[c].z; b.y = pk[c].w;
            *(uint2*)&Ks[buf][kr*KP + kc*8]     = a;
            *(uint2*)&Ks[buf][kr*KP + kc*8 + 4] = b;
            int vr = j >> 3, vc = j & 7;
            a.x = pv[c].x; a.y = pv[c].y; b.x = pv[c].z; b.y = pv[c].w;
            *(uint2*)&Vt[buf][vr*VP + vc*8]     = a;
            *(uint2*)&Vt[buf][vr*VP + vc*8 + 4] = b;
        }
    };

    // prologue: tile 0 -> buf0; tile 1 loads in flight
    LOADT(0);
    STORET(0);
    LOADT(1);                                 // nkt >= 2 always

    for (int kt = 0; kt < nkt; ++kt) {
        const int k0 = kt*64;
        const int cb = kt & 1;
        bar_lds();                            // buf[cb] staged for all waves

        // stage tile kt+1 (loads issued one full tile ago -> counted vmcnt),
        // then issue loads for kt+2 (in flight across the next barrier).
        if (kt + 1 < nkt) {
            STORET(cb ^ 1);
            if (kt + 2 < nkt) LOADT(kt + 2);
        }

        if (k0 <= qband + 31) {
            const u16* Kb = Ks[cb];
            const u16* Vb = Vt[cb];

            // ---- S^T = K · Q^T (Q pre-scaled: already exp2 domain) ----
            vf16 accS[2];
            #pragma unroll
            for (int kk = 0; kk < 2; ++kk)
                #pragma unroll
                for (int i = 0; i < 16; ++i) accS[kk][i] = 0.f;
            __builtin_amdgcn_s_setprio(1);
            #pragma unroll
            for (int s = 0; s < 8; ++s) {
                #pragma unroll
                for (int kk = 0; kk < 2; ++kk) {
                    s8v a = ld8(&Kb[(kk*32 + lane31)*KP + s*16 + q2*8]);
                    accS[kk] = __builtin_amdgcn_mfma_f32_32x32x16_bf16(a, qf[s], accS[kk], 0, 0, 0);
                }
            }
            __builtin_amdgcn_s_setprio(0);

            // ---- causal mask (tail tiles only) ----
            float p[2][16];
            const bool tail = (k0 + 63 > qband);
            #pragma unroll
            for (int kk = 0; kk < 2; ++kk)
                #pragma unroll
                for (int r = 0; r < 16; ++r) {
                    float sv = accS[kk][r];
                    if (tail) {
                        int keyg = k0 + kk*32 + (r & 3) + 8*(r >> 2) + 4*q2;
                        if (keyg > qrow) sv = -INFINITY;
                    }
                    p[kk][r] = sv;
                }

            // ---- fixed-shift softmax: P = exp2(s - 16), exact ----
            float ls0 = 0.f, ls1 = 0.f;
            #pragma unroll
            for (int r = 0; r < 16; ++r) {
                float e0 = __builtin_amdgcn_exp2f(p[0][r] - 16.f);
                float e1 = __builtin_amdgcn_exp2f(p[1][r] - 16.f);
                p[0][r] = e0; p[1][r] = e1;
                ls0 += e0; ls1 += e1;
            }
            float ls = ls0 + ls1;
            ls += __shfl_xor(ls, 32);
            lrow += ls;

            // ---- pack P (bf16 trunc) as PV A-fragments ----
            s8v pf[4];
            #pragma unroll
            for (int tau = 0; tau < 4; ++tau) {
                int kk = tau >> 1, rb = (tau & 1)*8;
                s8v v;
                #pragma unroll
                for (int j = 0; j < 8; ++j)
                    v[j] = (short)(__float_as_uint(p[kk][rb + j]) >> 16);
                pf[tau] = v;
            }

            // ---- O += P · V ----
            __builtin_amdgcn_s_setprio(1);
            #pragma unroll
            for (int dt = 0; dt < 4; ++dt) {
                const u16* vp = &Vb[(dt*32 + lane31)*VP];
                #pragma unroll
                for (int tau = 0; tau < 4; ++tau) {
                    const u16* q = vp + 16*tau + 4*q2;
                    short4 lo = *(const short4*)q;
                    short4 hi = *(const short4*)(q + 8);
                    s8v bvv = {lo.x, lo.y, lo.z, lo.w, hi.x, hi.y, hi.z, hi.w};
                    accO[dt] = __builtin_amdgcn_mfma_f32_32x32x16_bf16(pf[tau], bvv, accO[dt], 0, 0, 0);
                }
            }
            __builtin_amdgcn_s_setprio(0);
        }
    }

    // =================== fused output projection epilogue ===================
    bar_lds();                       // all waves done reading K/V LDS regions
    u16* Os  = &Ks[0][0];            // 128 x KP bf16 O tile (exact size match)
    u16* Wps = &Vt[0][0];            // 128 x KP bf16 Wp tile (fits in Vt)

    // normalized O -> LDS (each wave writes its own 32-row band)
    {
        float inv = 1.0f / lrow;
        #pragma unroll
        for (int r = 0; r < 16; ++r) {
            int rl = (r & 3) + 8*(r >> 2) + 4*q2;
            float ir = __shfl(inv, rl);
            u16* op = &Os[(32*w + rl)*KP];
            #pragma unroll
            for (int dt = 0; dt < 4; ++dt)
                op[dt*32 + lane31] = f2bf(accO[dt][r] * ir);
        }
    }
    // stage Wp (fp32 -> bf16)
    #pragma unroll
    for (int it = 0; it < 8; ++it) {
        int i = t + 256*it;
        int e = i >> 4, c8 = i & 15;
        st8(&Wps[e*KP + c8*8], ((const float4*)Wp)[2*i], ((const float4*)Wp)[2*i + 1]);
    }
    bar_lds();

    // out = O x Wp^T + bp
    {
        s8v af[8];
        #pragma unroll
        for (int s = 0; s < 8; ++s)
            af[s] = ld8(&Os[(w*32 + lane31)*KP + s*16 + q2*8]);

        vf16 acc[4];
        #pragma unroll
        for (int et = 0; et < 4; ++et)
            #pragma unroll
            for (int i = 0; i < 16; ++i) acc[et][i] = 0.f;

        #pragma unroll
        for (int s = 0; s < 8; ++s) {
            #pragma unroll
            for (int et = 0; et < 4; ++et) {
                s8v bf = ld8(&Wps[(et*32 + lane31)*KP + s*16 + q2*8]);
                acc[et] = __builtin_amdgcn_mfma_f32_32x32x16_bf16(af[s], bf, acc[et], 0, 0, 0);
            }
        }

        float bb[4];
        #pragma unroll
        for (int et = 0; et < 4; ++et) bb[et] = Bp[et*32 + lane31];

        const int b = bn >> 4, n = bn & 15;
        #pragma unroll
        for (int r = 0; r < 16; ++r) {
            int rl = (r & 3) + 8*(r >> 2) + 4*q2;
            int qg = q0 + w*32 + rl;
            size_t orow = ((size_t)(b*TT + qg)*NN + n) * DD;
            #pragma unroll
            for (int et = 0; et < 4; ++et)
                out[orow + et*32 + lane31] = acc[et][r] + bb[et];
        }
    }
}

extern "C" void kernel_launch(void* const* d_in, const int* in_sizes, int n_in,
                              void* d_out, int out_size, void* d_ws, size_t ws_size,
                              hipStream_t stream)
{
    const float* x  = (const float*)d_in[0];
    const float* wq = (const float*)d_in[1];
    const float* bq = (const float*)d_in[2];
    const float* wk = (const float*)d_in[3];
    const float* bk = (const float*)d_in[4];
    const float* wv = (const float*)d_in[5];
    const float* bv = (const float*)d_in[6];
    const float* wp = (const float*)d_in[7];
    const float* bp = (const float*)d_in[8];
    float* out = (float*)d_out;
    (void)d_ws; (void)ws_size;

    qkv_proj_kernel<<<dim3(NROWS/128), dim3(256), 0, stream>>>(
        x, wq, bq, wk, bk, wv, bv);
    attn_kernel<<<dim3(BB*NN*(TT/128)), dim3(256), 0, stream>>>(wp, bp, out);
}